// Round 1
// baseline (783.019 us; speedup 1.0000x reference)
//
#include <hip/hip_runtime.h>
#include <math.h>

// VQ-VAE quantizer. Outputs in d_out (float32, flat, concat):
//   [0] loss | [1..16777216] quantized_st NCHW | [16777217] perplexity
//   [16777218 ..) encodings one-hot [262144,512]
//
// R12: split the 512 MB encodings zero-fill OUT of vq_main into the prep
// kernel's grid (blocks 9..4104) as a pure streaming NT-store kernel —
// structurally identical to the ~6.2 TB/s rocclr fillBuffer (no barriers,
// no vmcnt(0) drains). Rationale: in R11 the zero stream was issued at
// vq_main's top and force-committed by the s_waitcnt vmcnt(0) the compiler
// emits before the pre-MFMA __syncthreads — every block stalled on 128 KB
// of HBM write commit before compute, ~3x off the write roofline.
// Stream order (prep -> main) guarantees the zeros land before the one-hot
// fixups, which shrink to ONE 4-byte NT store per token. No double-write,
// no ordering machinery inside vq_main.
//
//   vq_prep (4105 blocks): [0..7] emb -> bf16 ws[8192..]; [8] b_k ->
//     ws[512..1023]; [9..4104] encodings zero-fill (128 KB/block).
//   vq_main (4096 blocks, 64 tok): MFMA 16x16x32 bf16, A=x[tok][d],
//     B=e[code][d], D row=(lane>>4)*4+r, col=lane&15; score=fma(-2,dot,b_k);
//     ascending-code min + shfl_xor merge ((==, smaller idx) first-occurrence).
//
// ws (floats): [0..511] hist(int), [512..1023] b_k,
//              [1024..5119] loss partials, [8192..24575] e-bf16 (64 KB).

#define NTOK    262144
#define KCODES  512
#define DDIM    64
#define CSTRIDE 16384
#define IMG     1048576
#define QOFF    1
#define POFF    16777217
#define EOFF    16777218
#define EBF     8192
#define SUBFLT  32768      // floats per one-hot sub-region (64 rows x 512)

typedef short bf16x8 __attribute__((ext_vector_type(8)));
typedef float f32x4  __attribute__((ext_vector_type(4)));

__device__ __forceinline__ unsigned short f2bf(float f) {
    unsigned u = __float_as_uint(f);
    return (unsigned short)((u + 0x7fffu + ((u >> 16) & 1u)) >> 16);  // RTN
}

__device__ __forceinline__ float np_pairwise_sq64(const float* v) {
    float r[8];
#pragma unroll
    for (int j = 0; j < 8; ++j) r[j] = __fmul_rn(v[j], v[j]);
#pragma unroll
    for (int i = 8; i < 64; i += 8) {
#pragma unroll
        for (int j = 0; j < 8; ++j)
            r[j] = __fadd_rn(r[j], __fmul_rn(v[i + j], v[i + j]));
    }
    float s01 = __fadd_rn(r[0], r[1]);
    float s23 = __fadd_rn(r[2], r[3]);
    float s45 = __fadd_rn(r[4], r[5]);
    float s67 = __fadd_rn(r[6], r[7]);
    return __fadd_rn(__fadd_rn(s01, s23), __fadd_rn(s45, s67));
}

// blocks 0..7: emb -> bf16 scratch; block 8: b_k = ||e_k||^2;
// blocks 9..4104: encodings zero-fill (fillBuffer-style streaming writes).
__global__ __launch_bounds__(256) void vq_prep(const float* __restrict__ emb,
                                               float* __restrict__ out,
                                               float* __restrict__ ws) {
    const int tid = threadIdx.x, blk = blockIdx.x;
    if (blk >= 9) {
        // pure streaming zero-fill: 32 x f32x4 per thread, fully coalesced,
        // no barriers, no drains -> retires at HBM write BW.
        f32x4* sub4 = (f32x4*)(out + EOFF) + (size_t)(blk - 9) * 8192;
        const f32x4 z4 = {0.f, 0.f, 0.f, 0.f};
#pragma unroll
        for (int ii = 0; ii < 32; ++ii)
            __builtin_nontemporal_store(z4, sub4 + ii * 256 + tid);
        return;
    }
    if (blk < 8) {
        unsigned short* ebf = (unsigned short*)(ws + EBF);
#pragma unroll
        for (int ii = 0; ii < 16; ++ii) {
            int t = blk * 4096 + ii * 256 + tid;     // linear [code][d]
            ebf[t] = f2bf(emb[t]);
        }
    } else {
#pragma unroll
        for (int r = 0; r < 2; ++r) {
            const int k = tid * 2 + r;
            const float* e = emb + (size_t)k * DDIM;
            float v[64];
#pragma unroll
            for (int i = 0; i < 64; ++i) v[i] = e[i];
            ws[512 + k] = np_pairwise_sq64(v);
        }
    }
}

// ---- fused main: MFMA distances + argmin + quantized/loss/hist/fixups ----
__global__ __launch_bounds__(256) void vq_main(const float* __restrict__ in,
                                               const float* __restrict__ emb,
                                               float* __restrict__ out,
                                               float* __restrict__ ws) {
    __shared__ unsigned short xbf[64 * 68];      // [tok][d] bf16 +pad, 8.5 KB
    __shared__ float          bsh[512];
    __shared__ int            idx_sh[64];
    __shared__ float          red[4];

    const int tid = threadIdx.x, blk = blockIdx.x;
    const int T0 = blk * 64, b = T0 >> 14, hw0 = T0 & 16383;

    // input loads first (only these gate the pre-MFMA barrier now)
    const float4* gx = (const float4*)(in + (size_t)b * IMG + hw0);
    float4 g[4];
#pragma unroll
    for (int jj = 0; jj < 4; ++jj) {
        int t = tid + jj * 256;                  // t = c*16 + q
        g[jj] = gx[(size_t)(t >> 4) * (CSTRIDE / 4) + (t & 15)];
    }
    const float bk0 = ws[512 + tid];
    const float bk1 = ws[768 + tid];

    // stage x as bf16 transposed [tok][d]
#pragma unroll
    for (int jj = 0; jj < 4; ++jj) {
        int t = tid + jj * 256;
        int c = t >> 4, q = (t & 15) * 4;
        xbf[(q + 0) * 68 + c] = f2bf(g[jj].x);
        xbf[(q + 1) * 68 + c] = f2bf(g[jj].y);
        xbf[(q + 2) * 68 + c] = f2bf(g[jj].z);
        xbf[(q + 3) * 68 + c] = f2bf(g[jj].w);
    }
    bsh[tid]       = bk0;
    bsh[256 + tid] = bk1;
    __syncthreads();

    const int l = tid & 63, w = tid >> 6;            // lane, wave
    const int lm = l & 15, lg = l >> 4;

    // A-fragments: x[tok = w*16+lm][d = kt*32 + lg*8 + j]
    const bf16x8 a0 = *(const bf16x8*)(xbf + (w * 16 + lm) * 68 + lg * 8);
    const bf16x8 a1 = *(const bf16x8*)(xbf + (w * 16 + lm) * 68 + 32 + lg * 8);

    const unsigned short* ebf = (const unsigned short*)(ws + EBF);
    const unsigned short* ep  = ebf + lm * 64 + lg * 8;

    float dmin[4]; int idx[4];
#pragma unroll
    for (int r = 0; r < 4; ++r) { dmin[r] = 3.402823466e38f; idx[r] = 0; }
    const f32x4 zero = {0.f, 0.f, 0.f, 0.f};

#pragma unroll 4
    for (int nt = 0; nt < 32; ++nt) {                // codes ascending
        bf16x8 b0 = *(const bf16x8*)(ep + nt * 1024);
        bf16x8 b1 = *(const bf16x8*)(ep + nt * 1024 + 32);
        f32x4 acc = __builtin_amdgcn_mfma_f32_16x16x32_bf16(a0, b0, zero, 0, 0, 0);
        acc       = __builtin_amdgcn_mfma_f32_16x16x32_bf16(a1, b1, acc,  0, 0, 0);
        const int   code = nt * 16 + lm;
        const float bk   = bsh[code];
#pragma unroll
        for (int r = 0; r < 4; ++r) {                // token = w*16 + lg*4 + r
            float s = fmaf(-2.0f, acc[r], bk);
            if (s < dmin[r]) { dmin[r] = s; idx[r] = code; }
        }
    }

    // merge across the 16 code-lanes (xor over bits 0..3 of lane)
#pragma unroll
    for (int m = 1; m < 16; m <<= 1) {
#pragma unroll
        for (int r = 0; r < 4; ++r) {
            float od = __shfl_xor(dmin[r], m, 64);
            int   oi = __shfl_xor(idx[r],  m, 64);
            if (od < dmin[r] || (od == dmin[r] && oi < idx[r])) {
                dmin[r] = od; idx[r] = oi;
            }
        }
    }
    if (lm == 0) {
#pragma unroll
        for (int r = 0; r < 4; ++r) idx_sh[w * 16 + lg * 4 + r] = idx[r];
    }
    __syncthreads();   // idx_sh ready

    // epilogue: hist, quantized_st (x re-read from global, L2-hot), loss
    const int tl = tid & 63, chh = (tid >> 6) * 16;  // 4 lanes per token
    const int id = idx_sh[tl];
    if (tid < 64) atomicAdd((int*)ws + id, 1);

    const float* px = in  + (size_t)b * IMG + hw0 + tl;
    float*       q  = out + QOFF + (size_t)b * IMG + hw0 + tl;
    const float* e0 = emb + (size_t)id * DDIM + chh;

    float lsum = 0.f;
#pragma unroll
    for (int cc = 0; cc < 16; ++cc) {
        float x   = px[(size_t)(chh + cc) * CSTRIDE];
        float dqx = __fsub_rn(e0[cc], x);
        lsum = __fadd_rn(lsum, __fmul_rn(dqx, dqx));
        __builtin_nontemporal_store(__fadd_rn(x, dqx),
                                    q + (size_t)(chh + cc) * CSTRIDE);
    }
#pragma unroll
    for (int off = 32; off > 0; off >>= 1) lsum += __shfl_down(lsum, off, 64);
    if ((tid & 63) == 0) red[tid >> 6] = lsum;
    __syncthreads();
    if (tid == 0) ws[1024 + blk] = red[0] + red[1] + red[2] + red[3];

    // one-hot 1.0 fixup: zeros were laid down by vq_prep (prior kernel on
    // the stream -> ordering guaranteed). One 4-byte NT store per token.
    if (tid < 64) {
        const int ix = idx_sh[tid];
        __builtin_nontemporal_store(
            1.0f, out + EOFF + (size_t)blk * SUBFLT + tid * 512 + ix);
    }
}

__global__ void vq_final(float* __restrict__ out, const float* __restrict__ ws) {
    __shared__ float sl[512], sp[512];
    int t = threadIdx.x;                              // 512 threads, 1 block
    float s = 0.f;
#pragma unroll
    for (int r = 0; r < 8; ++r) s += ws[1024 + t + 512 * r];
    sl[t] = s;
    int cnt = ((const int*)ws)[t];
    float p = (float)cnt * (1.0f / 262144.0f);
    sp[t] = p * logf(p + 1e-10f);
    __syncthreads();
    for (int off = 256; off > 0; off >>= 1) {
        if (t < off) { sl[t] += sl[t + off]; sp[t] += sp[t + off]; }
        __syncthreads();
    }
    if (t == 0) {
        float m = sl[0] * (1.0f / 16777216.0f);       // /2^24 exact
        out[0]    = __fadd_rn(m, __fmul_rn(0.25f, m));
        out[POFF] = expf(-sp[0]);
    }
}

extern "C" void kernel_launch(void* const* d_in, const int* in_sizes, int n_in,
                              void* d_out, int out_size, void* d_ws, size_t ws_size,
                              hipStream_t stream) {
    const float* in  = (const float*)d_in[0];
    const float* emb = (const float*)d_in[1];
    float* out = (float*)d_out;
    float* ws  = (float*)d_ws;   // needs 98304 B; harness scratch is larger

    (void)hipMemsetAsync(d_ws, 0, 512 * sizeof(int), stream);      // histogram
    hipLaunchKernelGGL(vq_prep,  dim3(4105), dim3(256), 0, stream, emb, out, ws);
    hipLaunchKernelGGL(vq_main,  dim3(4096), dim3(256), 0, stream, in, emb, out, ws);
    hipLaunchKernelGGL(vq_final, dim3(1),    dim3(512), 0, stream, out, ws);
}

// Round 2
// 724.748 us; speedup vs baseline: 1.0804x; 1.0804x over previous
//
#include <hip/hip_runtime.h>
#include <math.h>

// VQ-VAE quantizer. Outputs in d_out (float32, flat, concat):
//   [0] loss | [1..16777216] quantized_st NCHW | [16777217] perplexity
//   [16777218 ..) encodings one-hot [262144,512]
//
// R13 = R11 (fused zero-stream, proven faster than split-R12) + forced
// occupancy. R12's experiment showed the fused 512 MB zero stream costs
// only ~30 us inside vq_main (vs 85 us standalone) -> main is NOT
// BW/drain-bound; it is latency-bound with ~no TLP. Per-block critical
// path (~150 VMEM x ~300cy ~= 19us) x 16 blocks/CU matches the measured
// ~305us only at ~1 block/CU occupancy -> VGPR blowup under plain
// __launch_bounds__(256) (up to 512 VGPR allowed) is the prime suspect.
// Fix: __launch_bounds__(256, 4) caps VGPR at 128 (4 blocks/CU, 16
// waves/CU); MFMA loop unroll 4->2 and epilogue unroll 16->4 to fit the
// budget without spills.
//
//   vq_prep (9 blocks): emb -> bf16 ws[8192..]; b_k -> ws[512..1023].
//   vq_main (4096 blocks, 64 tok): MFMA 16x16x32 bf16, A=x[tok][d],
//     B=e[code][d], D row=(lane>>4)*4+r, col=lane&15; score=fma(-2,dot,b_k);
//     ascending-code min + shfl_xor merge ((==, smaller idx) first-occurrence).
//
// ws (floats): [0..511] hist(int), [512..1023] b_k,
//              [1024..5119] loss partials, [8192..24575] e-bf16 (64 KB).

#define NTOK    262144
#define KCODES  512
#define DDIM    64
#define CSTRIDE 16384
#define IMG     1048576
#define QOFF    1
#define POFF    16777217
#define EOFF    16777218
#define EBF     8192
#define SUBFLT  32768      // floats per one-hot sub-region (64 rows x 512)

typedef short bf16x8 __attribute__((ext_vector_type(8)));
typedef float f32x4  __attribute__((ext_vector_type(4)));

__device__ __forceinline__ unsigned short f2bf(float f) {
    unsigned u = __float_as_uint(f);
    return (unsigned short)((u + 0x7fffu + ((u >> 16) & 1u)) >> 16);  // RTN
}

__device__ __forceinline__ float np_pairwise_sq64(const float* v) {
    float r[8];
#pragma unroll
    for (int j = 0; j < 8; ++j) r[j] = __fmul_rn(v[j], v[j]);
#pragma unroll
    for (int i = 8; i < 64; i += 8) {
#pragma unroll
        for (int j = 0; j < 8; ++j)
            r[j] = __fadd_rn(r[j], __fmul_rn(v[i + j], v[i + j]));
    }
    float s01 = __fadd_rn(r[0], r[1]);
    float s23 = __fadd_rn(r[2], r[3]);
    float s45 = __fadd_rn(r[4], r[5]);
    float s67 = __fadd_rn(r[6], r[7]);
    return __fadd_rn(__fadd_rn(s01, s23), __fadd_rn(s45, s67));
}

// blocks 0..7: emb -> bf16 scratch; block 8: b_k = ||e_k||^2
__global__ __launch_bounds__(256) void vq_prep(const float* __restrict__ emb,
                                               float* __restrict__ ws) {
    const int tid = threadIdx.x, blk = blockIdx.x;
    if (blk < 8) {
        unsigned short* ebf = (unsigned short*)(ws + EBF);
#pragma unroll
        for (int ii = 0; ii < 16; ++ii) {
            int t = blk * 4096 + ii * 256 + tid;     // linear [code][d]
            ebf[t] = f2bf(emb[t]);
        }
    } else {
#pragma unroll
        for (int r = 0; r < 2; ++r) {
            const int k = tid * 2 + r;
            const float* e = emb + (size_t)k * DDIM;
            float v[64];
#pragma unroll
            for (int i = 0; i < 64; ++i) v[i] = e[i];
            ws[512 + k] = np_pairwise_sq64(v);
        }
    }
}

// ---- fused main: MFMA distances + argmin + all output streams -----------
__global__ __launch_bounds__(256, 4) void vq_main(const float* __restrict__ in,
                                                  const float* __restrict__ emb,
                                                  float* __restrict__ out,
                                                  float* __restrict__ ws) {
    __shared__ unsigned short xbf[64 * 68];      // [tok][d] bf16 +pad, 8.5 KB
    __shared__ float          bsh[512];
    __shared__ int            idx_sh[64];
    __shared__ float          red[4];

    const int tid = threadIdx.x, blk = blockIdx.x;
    const int T0 = blk * 64, b = T0 >> 14, hw0 = T0 & 16383;

    // issue input loads first (oldest in vmcnt queue -> consumable while the
    // zero stores below are still in flight)
    const float4* gx = (const float4*)(in + (size_t)b * IMG + hw0);
    float4 g[4];
#pragma unroll
    for (int jj = 0; jj < 4; ++jj) {
        int t = tid + jj * 256;                  // t = c*16 + q
        g[jj] = gx[(size_t)(t >> 4) * (CSTRIDE / 4) + (t & 15)];
    }
    const float bk0 = ws[512 + tid];
    const float bk1 = ws[768 + tid];

    // one-hot ZERO stream: 128 KB/block, nontemporal fire-and-forget.
    // Drained by the pre-MFMA barrier; 1.0 fixups come after the merge
    // barrier -> ordering guaranteed (R6-proven pattern).
    f32x4* sub4 = (f32x4*)(out + EOFF + (size_t)blk * SUBFLT);
    const f32x4 z4 = {0.f, 0.f, 0.f, 0.f};
#pragma unroll
    for (int ii = 0; ii < 32; ++ii)
        __builtin_nontemporal_store(z4, sub4 + ii * 256 + tid);

    // stage x as bf16 transposed [tok][d]
#pragma unroll
    for (int jj = 0; jj < 4; ++jj) {
        int t = tid + jj * 256;
        int c = t >> 4, q = (t & 15) * 4;
        xbf[(q + 0) * 68 + c] = f2bf(g[jj].x);
        xbf[(q + 1) * 68 + c] = f2bf(g[jj].y);
        xbf[(q + 2) * 68 + c] = f2bf(g[jj].z);
        xbf[(q + 3) * 68 + c] = f2bf(g[jj].w);
    }
    bsh[tid]       = bk0;
    bsh[256 + tid] = bk1;
    __syncthreads();

    const int l = tid & 63, w = tid >> 6;            // lane, wave
    const int lm = l & 15, lg = l >> 4;

    // A-fragments: x[tok = w*16+lm][d = kt*32 + lg*8 + j]
    const bf16x8 a0 = *(const bf16x8*)(xbf + (w * 16 + lm) * 68 + lg * 8);
    const bf16x8 a1 = *(const bf16x8*)(xbf + (w * 16 + lm) * 68 + 32 + lg * 8);

    const unsigned short* ebf = (const unsigned short*)(ws + EBF);
    const unsigned short* ep  = ebf + lm * 64 + lg * 8;

    float dmin[4]; int idx[4];
#pragma unroll
    for (int r = 0; r < 4; ++r) { dmin[r] = 3.402823466e38f; idx[r] = 0; }
    const f32x4 zero = {0.f, 0.f, 0.f, 0.f};

#pragma unroll 2
    for (int nt = 0; nt < 32; ++nt) {                // codes ascending
        bf16x8 b0 = *(const bf16x8*)(ep + nt * 1024);
        bf16x8 b1 = *(const bf16x8*)(ep + nt * 1024 + 32);
        f32x4 acc = __builtin_amdgcn_mfma_f32_16x16x32_bf16(a0, b0, zero, 0, 0, 0);
        acc       = __builtin_amdgcn_mfma_f32_16x16x32_bf16(a1, b1, acc,  0, 0, 0);
        const int   code = nt * 16 + lm;
        const float bk   = bsh[code];
#pragma unroll
        for (int r = 0; r < 4; ++r) {                // token = w*16 + lg*4 + r
            float s = fmaf(-2.0f, acc[r], bk);
            if (s < dmin[r]) { dmin[r] = s; idx[r] = code; }
        }
    }

    // merge across the 16 code-lanes (xor over bits 0..3 of lane)
#pragma unroll
    for (int m = 1; m < 16; m <<= 1) {
#pragma unroll
        for (int r = 0; r < 4; ++r) {
            float od = __shfl_xor(dmin[r], m, 64);
            int   oi = __shfl_xor(idx[r],  m, 64);
            if (od < dmin[r] || (od == dmin[r] && oi < idx[r])) {
                dmin[r] = od; idx[r] = oi;
            }
        }
    }
    if (lm == 0) {
#pragma unroll
        for (int r = 0; r < 4; ++r) idx_sh[w * 16 + lg * 4 + r] = idx[r];
    }
    __syncthreads();   // idx_sh ready; zero stream drained (vmcnt(0))

    // epilogue: hist, quantized_st (x re-read from global, L2-hot), loss
    const int tl = tid & 63, chh = (tid >> 6) * 16;  // 4 lanes per token
    const int id = idx_sh[tl];
    if (tid < 64) atomicAdd((int*)ws + id, 1);

    const float* px = in  + (size_t)b * IMG + hw0 + tl;
    float*       q  = out + QOFF + (size_t)b * IMG + hw0 + tl;
    const float* e0 = emb + (size_t)id * DDIM + chh;

    float lsum = 0.f;
#pragma unroll 4
    for (int cc = 0; cc < 16; ++cc) {
        float x   = px[(size_t)(chh + cc) * CSTRIDE];
        float dqx = __fsub_rn(e0[cc], x);
        lsum = __fadd_rn(lsum, __fmul_rn(dqx, dqx));
        __builtin_nontemporal_store(__fadd_rn(x, dqx),
                                    q + (size_t)(chh + cc) * CSTRIDE);
    }
#pragma unroll
    for (int off = 32; off > 0; off >>= 1) lsum += __shfl_down(lsum, off, 64);
    if ((tid & 63) == 0) red[tid >> 6] = lsum;
    __syncthreads();
    if (tid == 0) ws[1024 + blk] = red[0] + red[1] + red[2] + red[3];

    // one-hot 1.0 fixups (ordered after the zero stream by barriers above)
    if (tid < 64) {
        const int ix = idx_sh[tid];
        f32x4 v = {0.f, 0.f, 0.f, 0.f};
        v[ix & 3] = 1.0f;
        __builtin_nontemporal_store(v, sub4 + tid * 128 + (ix >> 2));
    }
}

__global__ void vq_final(float* __restrict__ out, const float* __restrict__ ws) {
    __shared__ float sl[512], sp[512];
    int t = threadIdx.x;                              // 512 threads, 1 block
    float s = 0.f;
#pragma unroll
    for (int r = 0; r < 8; ++r) s += ws[1024 + t + 512 * r];
    sl[t] = s;
    int cnt = ((const int*)ws)[t];
    float p = (float)cnt * (1.0f / 262144.0f);
    sp[t] = p * logf(p + 1e-10f);
    __syncthreads();
    for (int off = 256; off > 0; off >>= 1) {
        if (t < off) { sl[t] += sl[t + off]; sp[t] += sp[t + off]; }
        __syncthreads();
    }
    if (t == 0) {
        float m = sl[0] * (1.0f / 16777216.0f);       // /2^24 exact
        out[0]    = __fadd_rn(m, __fmul_rn(0.25f, m));
        out[POFF] = expf(-sp[0]);
    }
}

extern "C" void kernel_launch(void* const* d_in, const int* in_sizes, int n_in,
                              void* d_out, int out_size, void* d_ws, size_t ws_size,
                              hipStream_t stream) {
    const float* in  = (const float*)d_in[0];
    const float* emb = (const float*)d_in[1];
    float* out = (float*)d_out;
    float* ws  = (float*)d_ws;   // needs 98304 B; harness scratch is larger

    (void)hipMemsetAsync(d_ws, 0, 512 * sizeof(int), stream);      // histogram
    hipLaunchKernelGGL(vq_prep,  dim3(9),    dim3(256), 0, stream, emb, ws);
    hipLaunchKernelGGL(vq_main,  dim3(4096), dim3(256), 0, stream, in, emb, out, ws);
    hipLaunchKernelGGL(vq_final, dim3(1),    dim3(512), 0, stream, out, ws);
}